// Round 1
// baseline (1455.061 us; speedup 1.0000x reference)
//
#include <hip/hip_runtime.h>
#include <hip/hip_bf16.h>

typedef __attribute__((ext_vector_type(8))) short short8;   // 8 bf16 = 4 VGPRs
typedef __attribute__((ext_vector_type(4))) float float4v;  // MFMA accumulator

#define HH 28
#define WD 28
#define CIN 64
#define COUT 128
#define KTOT 288          // 32 l * 3 j * 3 k
#define BSTRIDE 296       // padded K-stride (bf16 elems) for Bm rows: 592B, lane stride 148 dw -> 2-way bank alias (free)

// Transpose + bf16-convert W: Wbf[i][K] = bf16(W[K*128 + i]),  K = l*9 + j*3 + k
__global__ __launch_bounds__(256) void prep_w_kernel(const float* __restrict__ W,
                                                     __hip_bfloat16* __restrict__ Wbf) {
    int idx = blockIdx.x * 256 + threadIdx.x;
    if (idx >= COUT * KTOT) return;
    int i = idx / KTOT;
    int K = idx - i * KTOT;
    Wbf[idx] = __float2bfloat16(W[K * COUT + i]);
}

// One block per (h, m). 128 threads = 2 waves. Each wave: i in [wave*64, wave*64+64), w in [0,32).
__global__ __launch_bounds__(128) void conv_kernel(const float* __restrict__ x,
                                                   const __hip_bfloat16* __restrict__ Wbf,
                                                   float* __restrict__ out) {
    __shared__ float xs[CIN * 3 * WD];                        // [c][j][w], rows h-1..h+1 (zero OOB)
    __shared__ __align__(16) __hip_bfloat16 Bm[32 * BSTRIDE]; // [w][K] bf16, w padded to 32

    const int h = blockIdx.x;
    const int m = blockIdx.y;
    const int tid = threadIdx.x;

    // ---- stage x rows h-1..h+1, all 64 channels (coalesced) ----
    for (int idx = tid; idx < CIN * 3 * WD; idx += 128) {
        int c = idx / (3 * WD);
        int r = idx - c * (3 * WD);
        int j = r / WD;
        int w = r - j * WD;
        int hh = h + j - 1;
        float v = 0.f;
        if (hh >= 0 && hh < HH)
            v = x[((m * CIN + c) * HH + hh) * WD + w];
        xs[idx] = v;
    }
    __syncthreads();

    // ---- form B[w][K]: im2col with roll(w)+zero-pad(unfold) boundaries ----
    // B[w][K] = [0<=w+k-1<28]*xs[l][j][(w+k-2)%28] + [0<=w2+k-1<28]*xs[l+32][j][(w2+k-2)%28], w2=(w-1)%28
    for (int idx = tid; idx < KTOT * WD; idx += 128) {
        int K = idx / WD;
        int w = idx - K * WD;
        int l = K / 9;
        int rem = K - l * 9;
        int j = rem / 3;
        int k = rem - j * 3;
        float t1 = 0.f, t2 = 0.f;
        int a1 = w + k - 1;
        if (a1 >= 0 && a1 < 28) {
            int i1 = a1 - 1; if (i1 < 0) i1 = 27;      // (w+k-2) mod 28
            t1 = xs[l * 84 + j * 28 + i1];
        }
        int w2 = (w == 0) ? 27 : (w - 1);
        int a2 = w2 + k - 1;
        if (a2 >= 0 && a2 < 28) {
            int i2 = a2 - 1; if (i2 < 0) i2 = 27;
            t2 = xs[(l + 32) * 84 + j * 28 + i2];
        }
        Bm[w * BSTRIDE + K] = __float2bfloat16(t1 + t2);
    }
    // zero pad rows w=28..31 (read by nt=1 MFMA fragments)
    for (int idx = tid; idx < 4 * KTOT; idx += 128) {
        int w = 28 + idx / KTOT;
        int K = idx - (idx / KTOT) * KTOT;
        Bm[w * BSTRIDE + K] = __float2bfloat16(0.f);
    }
    __syncthreads();

    // ---- MFMA main loop: M=128, N=32(28), K=288 = 9 steps of 32 ----
    const int lane = tid & 63;
    const int wv = tid >> 6;          // wave id -> i half
    const int row = lane & 15;        // A: m-row / B: n-col
    const int q = lane >> 4;          // k-quad

    float4v acc[4][2] = {};           // [mt][nt], zero-init

    for (int s = 0; s < 9; ++s) {
        int k0 = s * 32 + q * 8;
        short8 afr[4], bfr[2];
        for (int mt = 0; mt < 4; ++mt) {
            int i = wv * 64 + mt * 16 + row;
            afr[mt] = *(const short8*)(&Wbf[i * KTOT + k0]);       // global, L2-resident, 16B/lane
        }
        for (int nt = 0; nt < 2; ++nt) {
            int wcol = nt * 16 + row;
            bfr[nt] = *(const short8*)(&Bm[wcol * BSTRIDE + k0]);  // ds_read_b128
        }
        for (int mt = 0; mt < 4; ++mt)
            for (int nt = 0; nt < 2; ++nt)
                acc[mt][nt] = __builtin_amdgcn_mfma_f32_16x16x32_bf16(afr[mt], bfr[nt], acc[mt][nt], 0, 0, 0);
    }

    // ---- epilogue: C/D layout col=lane&15, row=(lane>>4)*4+r ----
    for (int nt = 0; nt < 2; ++nt) {
        int w = nt * 16 + row;
        if (w >= 28) continue;
        for (int mt = 0; mt < 4; ++mt) {
            int ibase = wv * 64 + mt * 16 + q * 4;
            float* op = &out[((m * COUT + ibase) * HH + h) * WD + w];
            for (int r = 0; r < 4; ++r)
                op[r * (HH * WD)] = acc[mt][nt][r];
        }
    }
}

extern "C" void kernel_launch(void* const* d_in, const int* in_sizes, int n_in,
                              void* d_out, int out_size, void* d_ws, size_t ws_size,
                              hipStream_t stream) {
    const float* x = (const float*)d_in[0];   // (1024, 64, 28, 28) fp32
    const float* W = (const float*)d_in[1];   // (32, 3, 3, 128) fp32
    float* out = (float*)d_out;               // (1024, 128, 28, 28) fp32
    __hip_bfloat16* Wbf = (__hip_bfloat16*)d_ws;  // 128*288 bf16 = 73728 B

    prep_w_kernel<<<(COUT * KTOT + 255) / 256, 256, 0, stream>>>(W, Wbf);
    conv_kernel<<<dim3(HH, 1024), 128, 0, stream>>>(x, Wbf, out);
}